// Round 3
// baseline (885.911 us; speedup 1.0000x reference)
//
#include <hip/hip_runtime.h>
#include <stdint.h>

// Word2MatEncoder: out[b] = prod_{s=0..63} table[sent[b,s]]  (28x28 fp32 chain)
//
// R3: eliminate the 390 MB/launch scratch round-trip seen in R1/R2.
//  - B matrices staged HBM->LDS via global_load_lds (no VGPR staging array).
//  - cur/acc ping-pong (no per-step 224B register-array copy).
//  - 7 lanes x 4 rows per task, 9 tasks/wave: halves LDS broadcast traffic
//    vs 14x2 (per-task LDS bytes scale with lanes/task).
//  - single 28KB LDS buffer, row-split software pipeline with hand-placed
//    s_waitcnt vmcnt(14): DMA of next matrix's rows overlaps FMAs on current.
// fp32 throughout (no fp32 MFMA on CDNA4; bf16 error compounds over 63 muls).

#define D 28
#define EMB 784
#define SEQ 64
#define NITEMS 2048
#define LPI 7            // lanes per task
#define IPW 9            // tasks per wave (63 of 64 lanes active)
#define RPL 4            // rows of the running product per lane
#define CHUNK_F 256      // floats per row-chunk in LDS (1KB: 63 lanes*16B + 16B dead)
#define BUF_F (D * CHUNK_F)  // 7168 floats = 28672 B

typedef __attribute__((address_space(3))) uint32_t lds_u32;
typedef const __attribute__((address_space(1))) uint32_t glb_u32;

// Stage rows [KLO,KHI) of matrix g0 (row-major 28x28) into the LDS buffer.
// Row k -> chunk at lbase + k*CHUNK_F; HW writes each lane's 16B at lane*16,
// so slot s's (k,jv) float4 lands at k*CHUNK_F + s*28 + jv*4  (s=lane/7, jv=lane%7).
// Lane 63 writes the 16B dead zone at chunk offset 1008 (harmless mirror).
template <int KLO, int KHI>
__device__ __forceinline__ void dma_rows(const float* g0, float* lbase, int rl) {
  const float* g = g0 + rl * 4;
#pragma unroll
  for (int k = KLO; k < KHI; ++k) {
    __builtin_amdgcn_global_load_lds((glb_u32*)(g + k * D),
                                     (lds_u32*)(lbase + k * CHUNK_F), 16, 0, 0);
  }
}

// C[r][:] (+)= A[r][k] * Brow_k  for k in [KLO,KHI). KLO==0 initializes C.
template <int KLO, int KHI>
__device__ __forceinline__ void mm_rows(const float* __restrict__ Bs,
                                        const float (&A)[RPL][D],
                                        float (&C)[RPL][D]) {
#pragma unroll
  for (int k = KLO; k < KHI; ++k) {
#pragma unroll
    for (int jv = 0; jv < 7; ++jv) {
      float4 m = *(const float4*)(Bs + k * CHUNK_F + jv * 4);
#pragma unroll
      for (int r = 0; r < RPL; ++r) {
        float a = A[r][k];
        if (k == 0) {
          C[r][4 * jv + 0] = a * m.x;
          C[r][4 * jv + 1] = a * m.y;
          C[r][4 * jv + 2] = a * m.z;
          C[r][4 * jv + 3] = a * m.w;
        } else {
          C[r][4 * jv + 0] = fmaf(a, m.x, C[r][4 * jv + 0]);
          C[r][4 * jv + 1] = fmaf(a, m.y, C[r][4 * jv + 1]);
          C[r][4 * jv + 2] = fmaf(a, m.z, C[r][4 * jv + 2]);
          C[r][4 * jv + 3] = fmaf(a, m.w, C[r][4 * jv + 3]);
        }
      }
    }
  }
}

// One chain step: C = A @ M_s (M_s already staged in LDS), while DMA-ing M_{s+1}
// (if HN) into the rows just consumed. Waits are fine-grained vmcnt(14): the
// newest 14 outstanding DMAs are always the half we do NOT need yet.
template <bool HN>
__device__ __forceinline__ void chain_step(const float* Bs, float* lbase,
                                           const float* gnext, int rl,
                                           const float (&A)[RPL][D],
                                           float (&C)[RPL][D]) {
  asm volatile("s_waitcnt vmcnt(14)" ::: "memory");  // rows 0..13 of M_s ready
  mm_rows<0, 14>(Bs, A, C);
  if constexpr (HN) {
    asm volatile("" ::: "memory");
    dma_rows<0, 14>(gnext, lbase, rl);               // overwrite consumed rows
    asm volatile("s_waitcnt vmcnt(14)" ::: "memory");// rows 14..27 of M_s ready
  } else {
    asm volatile("s_waitcnt vmcnt(0)" ::: "memory");
  }
  mm_rows<14, D>(Bs, A, C);
  if constexpr (HN) {
    asm volatile("" ::: "memory");
    dma_rows<14, D>(gnext, lbase, rl);
  }
}

// Product of SEG_LEN consecutive matrices (SEG_LEN even -> result ends in B).
// GATHER: matrices are table[sp[s]]; else dense at src + (task*SEG_LEN+s)*EMB.
template <int SEG_LEN, int PSEG, bool GATHER>
__global__ __launch_bounds__(64, 2) void chain_kernel(
    const float* __restrict__ src, const int* __restrict__ sent,
    float* __restrict__ dst, int ntask) {
  __shared__ __align__(16) float lds[BUF_F];

  const int lane = threadIdx.x;
  int slot = lane / LPI;
  int rl = lane - slot * LPI;
  if (slot >= IPW) { slot = IPW - 1; rl = LPI - 1; }  // lane 63 mirrors lane 62
  int task = blockIdx.x * IPW + slot;
  if (task >= ntask) task = ntask - 1;  // tail duplicates (same values, benign)

  const int* sp = nullptr;
  if (GATHER) {
    const int item = task / PSEG;
    const int seg = task - item * PSEG;
    sp = sent + item * SEQ + seg * SEG_LEN;
  }
  auto mat_ptr = [&](int s) -> const float* {
    if (GATHER) return src + (size_t)sp[s] * EMB;
    return src + ((size_t)task * SEG_LEN + s) * EMB;
  };

  float A[RPL][D], B[RPL][D];

  // A = rows rl*4 .. rl*4+3 of the first matrix (direct global loads)
  {
    const float* m0 = mat_ptr(0);
#pragma unroll
    for (int r = 0; r < RPL; ++r) {
      const float* rp = m0 + (rl * RPL + r) * D;
#pragma unroll
      for (int jv = 0; jv < 7; ++jv) {
        float4 v = *(const float4*)(rp + 4 * jv);
        A[r][4 * jv + 0] = v.x;
        A[r][4 * jv + 1] = v.y;
        A[r][4 * jv + 2] = v.z;
        A[r][4 * jv + 3] = v.w;
      }
    }
  }

  // stage matrix 1 fully (both halves)
  dma_rows<0, D>(mat_ptr(1), lds, rl);

  const float* Bs = lds + slot * (LPI * 4);  // slot*28 floats: bank-spread, 16B aligned
  int s = 1;
  constexpr int NP = (SEG_LEN - 1) / 2;  // SEG_LEN even: NP pairs + 1 leftover step
#pragma unroll 1
  for (int p = 0; p < NP; ++p) {
    chain_step<true>(Bs, lds, mat_ptr(s + 1), rl, A, B); ++s;
    chain_step<true>(Bs, lds, mat_ptr(s + 1), rl, B, A); ++s;
  }
  chain_step<false>(Bs, lds, nullptr, rl, A, B);  // result in B

  // store
  {
    float* op = dst + (size_t)task * EMB;
#pragma unroll
    for (int r = 0; r < RPL; ++r) {
      float* rp = op + (rl * RPL + r) * D;
#pragma unroll
      for (int jv = 0; jv < 7; ++jv) {
        *(float4*)(rp + 4 * jv) =
            make_float4(B[r][4 * jv + 0], B[r][4 * jv + 1],
                        B[r][4 * jv + 2], B[r][4 * jv + 3]);
      }
    }
  }
}

extern "C" void kernel_launch(void* const* d_in, const int* in_sizes, int n_in,
                              void* d_out, int out_size, void* d_ws, size_t ws_size,
                              hipStream_t stream) {
  const float* table = (const float*)d_in[0];
  const int* sent = (const int*)d_in[1];
  float* out = (float*)d_out;

  const size_t need = (size_t)NITEMS * 4 * EMB * sizeof(float);  // 25.7 MB
  if (ws_size >= need) {
    float* p = (float*)d_ws;
    // phase 1: 4 segments of 16 per item -> 8192 partials (contiguous per item)
    const int ntask1 = NITEMS * 4;
    chain_kernel<16, 4, true><<<(ntask1 + IPW - 1) / IPW, 64, 0, stream>>>(
        table, sent, p, ntask1);
    // phase 2: chain each item's 4 partials -> d_out
    chain_kernel<4, 1, false><<<(NITEMS + IPW - 1) / IPW, 64, 0, stream>>>(
        p, nullptr, out, NITEMS);
  } else {
    // fallback: direct 64-long chain per item straight into d_out
    chain_kernel<64, 1, true><<<(NITEMS + IPW - 1) / IPW, 64, 0, stream>>>(
        table, sent, out, NITEMS);
  }
}

// Round 4
// 320.218 us; speedup vs baseline: 2.7666x; 2.7666x over previous
//
#include <hip/hip_runtime.h>
#include <stdint.h>

// Word2MatEncoder: out[b] = prod_{s=0..63} table[sent[b,s]]  (28x28 fp32 chain)
//
// R4: R2's proven single-wave structure, with the register-prefetch spill
// removed via global_load_lds staging (0 staging VGPRs) and the R3 SROA
// disaster avoided: one flat body, macro ping-pong on named arrays (A0/A1),
// no inline asm, no array references across calls.
//  - 14 lanes/task, 2 rows of the running product per lane, 4 tasks/wave.
//    Live set ~135 VGPRs -> no spill.
//  - DMA layout: chunk t (1 KiB) holds rows {2t,2t+1} of all 4 slot matrices;
//    lane l writes at t*1024 + l*16 (HW rule). Read offsets are compile-time:
//    slot s, row k, jv -> (k>>1)*256 + s*56 + (k&1)*28 + 4*jv floats.
//    Slot bases hit banks {0,24,16,8}: broadcast ds_read_b128 conflict-free.
//  - Single 14.3 KB buffer -> 11 blocks/CU capacity (grid needs 8/CU);
//    2 waves/SIMD TLP hides the per-step DMA latency (~400 cy vs 3136 cy FMA).
// fp32 throughout (no fp32 MFMA on CDNA4; bf16 error compounds over 63 muls).

#define D 28
#define EMB 784
#define SEQ 64
#define NITEMS 2048
#define LPI 14           // lanes per task
#define IPW 4            // tasks per wave (56 of 64 lanes active)
#define RPL 2            // rows of the running product per lane
#define NCHUNK 14        // DMA chunks per matrix-set (2 rows x 4 slots each)
#define CHUNK_F 256      // floats per chunk (64 lanes x 16B)
#define BUF_F (NCHUNK * CHUNK_F)  // 3584 floats = 14336 B

typedef __attribute__((address_space(3))) uint32_t lds_u32;
typedef const __attribute__((address_space(1))) uint32_t glb_u32;

// Stage one matrix per slot into LDS. glane = matrix base + rl*16B (per lane);
// chunk t pulls bytes [t*224, t*224+16) of each slot's matrix per lane.
__device__ __forceinline__ void dma_mat(const float* glane, float* lds0) {
#pragma unroll
  for (int t = 0; t < NCHUNK; ++t)
    __builtin_amdgcn_global_load_lds((glb_u32*)(glane + t * 56),
                                     (lds_u32*)(lds0 + t * CHUNK_F), 16, 0, 0);
}

// Cc = Aa @ M   (M staged in LDS at Bs with the chunk layout above)
#define MATMUL(Aa, Cc)                                                         \
  do {                                                                         \
    _Pragma("unroll") for (int k = 0; k < D; ++k) {                            \
      _Pragma("unroll") for (int jv = 0; jv < 7; ++jv) {                       \
        float4 m =                                                             \
            *(const float4*)(Bs + (k >> 1) * CHUNK_F + (k & 1) * 28 + 4 * jv); \
        _Pragma("unroll") for (int r = 0; r < RPL; ++r) {                      \
          float a = Aa[r][k];                                                  \
          if (k == 0) {                                                        \
            Cc[r][4 * jv + 0] = a * m.x;                                       \
            Cc[r][4 * jv + 1] = a * m.y;                                       \
            Cc[r][4 * jv + 2] = a * m.z;                                       \
            Cc[r][4 * jv + 3] = a * m.w;                                       \
          } else {                                                             \
            Cc[r][4 * jv + 0] = fmaf(a, m.x, Cc[r][4 * jv + 0]);               \
            Cc[r][4 * jv + 1] = fmaf(a, m.y, Cc[r][4 * jv + 1]);               \
            Cc[r][4 * jv + 2] = fmaf(a, m.z, Cc[r][4 * jv + 2]);               \
            Cc[r][4 * jv + 3] = fmaf(a, m.w, Cc[r][4 * jv + 3]);               \
          }                                                                    \
        }                                                                      \
      }                                                                        \
    }                                                                          \
  } while (0)

// One chain step: wait staged matrix, multiply, then DMA the next one.
#define STEP(Aa, Cc)                                                           \
  do {                                                                         \
    __builtin_amdgcn_s_waitcnt(0x0f70); /* vmcnt(0): matrix landed */          \
    __syncthreads();                                                           \
    MATMUL(Aa, Cc);                                                            \
    __syncthreads(); /* all LDS reads drained before overwrite */              \
    if (s + 1 < SEG_LEN) {                                                     \
      dma_mat(gn, lds);                                                        \
      int nn = (s + 2 < SEG_LEN) ? s + 2 : SEG_LEN - 1;                        \
      gn = glane(nn);                                                          \
    }                                                                          \
    ++s;                                                                       \
  } while (0)

// Product of SEG_LEN consecutive matrices (SEG_LEN-1 odd -> result in A1).
// GATHER: matrices are table[sp[s]]; else dense at src + (task*SEG_LEN+s)*EMB.
template <int SEG_LEN, int PSEG, bool GATHER>
__global__ __launch_bounds__(64, 1) void chain_kernel(
    const float* __restrict__ src, const int* __restrict__ sent,
    float* __restrict__ dst, int ntask) {
  __shared__ __align__(16) float lds[BUF_F];

  const int lane = threadIdx.x;
  int slot = lane / LPI;
  int rl = lane - slot * LPI;
  if (slot >= IPW) { slot = IPW - 1; rl = LPI - 1; }  // lanes 56-63 mirror lane 55
  int task = blockIdx.x * IPW + slot;
  if (task >= ntask) task = ntask - 1;  // tail duplicates (same values, benign)

  const int* sp = nullptr;
  if (GATHER) {
    const int item = task / PSEG;
    const int seg = task - item * PSEG;
    sp = sent + item * SEQ + seg * SEG_LEN;
  }
  auto glane = [&](int s) -> const float* {
    const float* m = GATHER ? src + (size_t)sp[s] * EMB
                            : src + ((size_t)task * SEG_LEN + s) * EMB;
    return m + rl * 4;  // this lane's 16B column within each 224B chunk-slice
  };

  float A0[RPL][D], A1[RPL][D];

  // A0 = this lane's rows (rl*2, rl*2+1) of the first matrix (direct loads)
  {
    const float* m0 = GATHER ? src + (size_t)sp[0] * EMB
                             : src + (size_t)task * SEG_LEN * EMB;
#pragma unroll
    for (int r = 0; r < RPL; ++r) {
      const float* rp = m0 + (rl * RPL + r) * D;
#pragma unroll
      for (int jv = 0; jv < 7; ++jv) {
        float4 v = *(const float4*)(rp + 4 * jv);
        A0[r][4 * jv + 0] = v.x;
        A0[r][4 * jv + 1] = v.y;
        A0[r][4 * jv + 2] = v.z;
        A0[r][4 * jv + 3] = v.w;
      }
    }
  }

  // stage matrix 1; prefetch pointer for matrix 2
  dma_mat(glane(1), lds);
  const float* gn = glane(SEG_LEN > 2 ? 2 : 1);
  const float* Bs = lds + slot * 56;

  int s = 1;
#pragma unroll 1
  for (int p = 0; p < (SEG_LEN - 1) / 2; ++p) {
    STEP(A0, A1);
    STEP(A1, A0);
  }
  STEP(A0, A1);  // final step (SEG_LEN-1 is odd) -> result in A1

  // store
  {
    float* op = dst + (size_t)task * EMB;
#pragma unroll
    for (int r = 0; r < RPL; ++r) {
      float* rp = op + (rl * RPL + r) * D;
#pragma unroll
      for (int jv = 0; jv < 7; ++jv) {
        *(float4*)(rp + 4 * jv) =
            make_float4(A1[r][4 * jv + 0], A1[r][4 * jv + 1],
                        A1[r][4 * jv + 2], A1[r][4 * jv + 3]);
      }
    }
  }
}

extern "C" void kernel_launch(void* const* d_in, const int* in_sizes, int n_in,
                              void* d_out, int out_size, void* d_ws, size_t ws_size,
                              hipStream_t stream) {
  const float* table = (const float*)d_in[0];
  const int* sent = (const int*)d_in[1];
  float* out = (float*)d_out;

  const size_t need = (size_t)NITEMS * 4 * EMB * sizeof(float);  // 25.7 MB
  if (ws_size >= need) {
    float* p = (float*)d_ws;
    // phase 1: 4 segments of 16 per item -> 8192 partials (contiguous per item)
    const int ntask1 = NITEMS * 4;
    chain_kernel<16, 4, true><<<(ntask1 + IPW - 1) / IPW, 64, 0, stream>>>(
        table, sent, p, ntask1);
    // phase 2: chain each item's 4 partials -> d_out
    chain_kernel<4, 1, false><<<(NITEMS + IPW - 1) / IPW, 64, 0, stream>>>(
        p, nullptr, out, NITEMS);
  } else {
    // fallback: direct 64-long chain per item straight into d_out
    chain_kernel<64, 1, true><<<(NITEMS + IPW - 1) / IPW, 64, 0, stream>>>(
        table, sent, out, NITEMS);
  }
}

// Round 5
// 262.004 us; speedup vs baseline: 3.3813x; 1.2222x over previous
//
#include <hip/hip_runtime.h>
#include <stdint.h>

// Word2MatEncoder: out[b] = prod_{s=0..63} table[sent[b,s]]  (28x28 fp32 chain)
//
// R5: R4 was LDS-return-BW bound (each lane re-reads the whole B matrix;
// traffic scales with lanes/task). Switch 14x2 -> 7 lanes x 4 rows per task,
// 9 tasks/wave: halves total ds_read instruction count at equal FLOPs.
// Keep the R4 skeleton exactly (flat body, macro ping-pong on NAMED arrays,
// global_load_lds staging = 0 staging VGPRs, no inline asm) -- that pattern
// is proven spill-free. Live set ~224+overhead VGPRs; launch_bounds(64,1)
// allows up to 512, and at 911 blocks (3.6/CU) 1 wave/SIMD is all we need.
//  - DMA layout: chunk t (1 KiB = 64 lanes x 16 B) holds row t of all 9 slot
//    matrices (7 lanes x 16 B = 28 floats per slot). Lane l writes at
//    t*1024 + l*16 (HW rule). Read offset: slot*28 + k*256 + 4*jv floats.
//    Slot bases at float offsets 28*s -> worst 2-way bank alias (free).
//  - 28 KB LDS -> 5 blocks/CU capacity >= 4 needed. No barriers removed:
//    1-wave blocks make __syncthreads cheap.
// fp32 throughout (no fp32 MFMA on CDNA4; bf16 error compounds over 63 muls).

#define D 28
#define EMB 784
#define SEQ 64
#define NITEMS 2048
#define LPI 7            // lanes per task
#define IPW 9            // tasks per wave (63 of 64 lanes active)
#define RPL 4            // rows of the running product per lane
#define NCHUNK 28        // DMA chunks per matrix-set (1 row x 9 slots each)
#define CHUNK_F 256      // floats per chunk (64 lanes x 16B)
#define BUF_F (NCHUNK * CHUNK_F)  // 7168 floats = 28672 B

typedef __attribute__((address_space(3))) uint32_t lds_u32;
typedef const __attribute__((address_space(1))) uint32_t glb_u32;

// Stage one matrix per slot into LDS. glane = matrix base + rl*16B (per lane);
// chunk t pulls row t (bytes [t*112, t*112+16) per lane) of each slot's matrix.
__device__ __forceinline__ void dma_mat(const float* glane, float* lds0) {
#pragma unroll
  for (int t = 0; t < NCHUNK; ++t)
    __builtin_amdgcn_global_load_lds((glb_u32*)(glane + t * D),
                                     (lds_u32*)(lds0 + t * CHUNK_F), 16, 0, 0);
}

// Cc = Aa @ M   (M staged in LDS at Bs with the chunk layout above)
#define MATMUL(Aa, Cc)                                                         \
  do {                                                                         \
    _Pragma("unroll") for (int k = 0; k < D; ++k) {                            \
      _Pragma("unroll") for (int jv = 0; jv < 7; ++jv) {                       \
        float4 m = *(const float4*)(Bs + k * CHUNK_F + 4 * jv);                \
        _Pragma("unroll") for (int r = 0; r < RPL; ++r) {                      \
          float a = Aa[r][k];                                                  \
          if (k == 0) {                                                        \
            Cc[r][4 * jv + 0] = a * m.x;                                       \
            Cc[r][4 * jv + 1] = a * m.y;                                       \
            Cc[r][4 * jv + 2] = a * m.z;                                       \
            Cc[r][4 * jv + 3] = a * m.w;                                       \
          } else {                                                             \
            Cc[r][4 * jv + 0] = fmaf(a, m.x, Cc[r][4 * jv + 0]);               \
            Cc[r][4 * jv + 1] = fmaf(a, m.y, Cc[r][4 * jv + 1]);               \
            Cc[r][4 * jv + 2] = fmaf(a, m.z, Cc[r][4 * jv + 2]);               \
            Cc[r][4 * jv + 3] = fmaf(a, m.w, Cc[r][4 * jv + 3]);               \
          }                                                                    \
        }                                                                      \
      }                                                                        \
    }                                                                          \
  } while (0)

// One chain step: wait staged matrix, multiply, then DMA the next one.
#define STEP(Aa, Cc)                                                           \
  do {                                                                         \
    __builtin_amdgcn_s_waitcnt(0x0f70); /* vmcnt(0): matrix landed */          \
    __syncthreads();                                                           \
    MATMUL(Aa, Cc);                                                            \
    __syncthreads(); /* all LDS reads drained before overwrite */              \
    if (s + 1 < SEG_LEN) {                                                     \
      dma_mat(gn, lds);                                                        \
      int nn = (s + 2 < SEG_LEN) ? s + 2 : SEG_LEN - 1;                        \
      gn = glane(nn);                                                          \
    }                                                                          \
    ++s;                                                                       \
  } while (0)

// Product of SEG_LEN consecutive matrices (SEG_LEN-1 odd -> result in A1).
// GATHER: matrices are table[sp[s]]; else dense at src + (task*SEG_LEN+s)*EMB.
template <int SEG_LEN, int PSEG, bool GATHER>
__global__ __launch_bounds__(64, 1) void chain_kernel(
    const float* __restrict__ src, const int* __restrict__ sent,
    float* __restrict__ dst, int ntask) {
  __shared__ __align__(16) float lds[BUF_F];

  const int lane = threadIdx.x;
  int slot = lane / LPI;
  int rl = lane - slot * LPI;
  if (slot >= IPW) { slot = IPW - 1; rl = LPI - 1; }  // lane 63 mirrors lane 62
  int task = blockIdx.x * IPW + slot;
  if (task >= ntask) task = ntask - 1;  // tail duplicates (same values, benign)

  const int* sp = nullptr;
  if (GATHER) {
    const int item = task / PSEG;
    const int seg = task - item * PSEG;
    sp = sent + item * SEQ + seg * SEG_LEN;
  }
  auto glane = [&](int s) -> const float* {
    const float* m = GATHER ? src + (size_t)sp[s] * EMB
                            : src + ((size_t)task * SEG_LEN + s) * EMB;
    return m + rl * 4;  // this lane's 16B slice of each row
  };

  float A0[RPL][D], A1[RPL][D];

  // A0 = this lane's rows (rl*4 .. rl*4+3) of the first matrix (direct loads)
  {
    const float* m0 = GATHER ? src + (size_t)sp[0] * EMB
                             : src + (size_t)task * SEG_LEN * EMB;
#pragma unroll
    for (int r = 0; r < RPL; ++r) {
      const float* rp = m0 + (rl * RPL + r) * D;
#pragma unroll
      for (int jv = 0; jv < 7; ++jv) {
        float4 v = *(const float4*)(rp + 4 * jv);
        A0[r][4 * jv + 0] = v.x;
        A0[r][4 * jv + 1] = v.y;
        A0[r][4 * jv + 2] = v.z;
        A0[r][4 * jv + 3] = v.w;
      }
    }
  }

  // stage matrix 1; prefetch pointer for matrix 2
  dma_mat(glane(1), lds);
  const float* gn = glane(SEG_LEN > 2 ? 2 : 1);
  const float* Bs = lds + slot * (LPI * 4);  // slot*28 floats

  int s = 1;
#pragma unroll 1
  for (int p = 0; p < (SEG_LEN - 1) / 2; ++p) {
    STEP(A0, A1);
    STEP(A1, A0);
  }
  STEP(A0, A1);  // final step (SEG_LEN-1 is odd) -> result in A1

  // store
  {
    float* op = dst + (size_t)task * EMB;
#pragma unroll
    for (int r = 0; r < RPL; ++r) {
      float* rp = op + (rl * RPL + r) * D;
#pragma unroll
      for (int jv = 0; jv < 7; ++jv) {
        *(float4*)(rp + 4 * jv) =
            make_float4(A1[r][4 * jv + 0], A1[r][4 * jv + 1],
                        A1[r][4 * jv + 2], A1[r][4 * jv + 3]);
      }
    }
  }
}

extern "C" void kernel_launch(void* const* d_in, const int* in_sizes, int n_in,
                              void* d_out, int out_size, void* d_ws, size_t ws_size,
                              hipStream_t stream) {
  const float* table = (const float*)d_in[0];
  const int* sent = (const int*)d_in[1];
  float* out = (float*)d_out;

  const size_t need = (size_t)NITEMS * 4 * EMB * sizeof(float);  // 25.7 MB
  if (ws_size >= need) {
    float* p = (float*)d_ws;
    // phase 1: 4 segments of 16 per item -> 8192 partials (contiguous per item)
    const int ntask1 = NITEMS * 4;
    chain_kernel<16, 4, true><<<(ntask1 + IPW - 1) / IPW, 64, 0, stream>>>(
        table, sent, p, ntask1);
    // phase 2: chain each item's 4 partials -> d_out
    chain_kernel<4, 1, false><<<(NITEMS + IPW - 1) / IPW, 64, 0, stream>>>(
        p, nullptr, out, NITEMS);
  } else {
    // fallback: direct 64-long chain per item straight into d_out
    chain_kernel<64, 1, true><<<(NITEMS + IPW - 1) / IPW, 64, 0, stream>>>(
        table, sent, out, NITEMS);
  }
}